// Round 12
// baseline (50.603 us; speedup 1.0000x reference)
//
#include <hip/hip_runtime.h>
#include <hip/hip_bf16.h>
#include <math.h>

#define W_SEQ   2048
#define C_IN    512
#define N_BATCH 4
#define NHEAD   8
#define QKV_CH  1536
#define OUT_CH  512
#define ATTND   512
#define N1_4    (QKV_CH * C_IN / 4)
#define N2_4    (OUT_CH * ATTND / 4)

typedef __attribute__((ext_vector_type(8))) short bf16x8;
typedef __attribute__((ext_vector_type(8))) unsigned short u16x8;
typedef __attribute__((ext_vector_type(4))) float f32x4;

__device__ __forceinline__ void gld16(const void* g, void* l) {
    __builtin_amdgcn_global_load_lds((const __attribute__((address_space(1))) void*)g,
                                     (__attribute__((address_space(3))) void*)l, 16, 0, 0);
}
__device__ __forceinline__ unsigned short f2bf(float f) {
    unsigned u = __float_as_uint(f);
    return (unsigned short)((u + 0x7FFFu + ((u >> 16) & 1u)) >> 16);
}
__device__ __forceinline__ unsigned ld_flag(const unsigned* p) {
    return __hip_atomic_load(p, __ATOMIC_RELAXED, __HIP_MEMORY_SCOPE_AGENT);
}

// ---------------------------------------------------------------------------
// Flag region (counters 64 B apart; zeroed by hipMemsetAsync each launch):
//   xdone[64]  @ 0      : X 128-row panel ready     (16 P0 arrivals each)
//   wpanel[12] @ 4096   : W_in 128-row panel ready  (64 P0 arrivals each)
//   wfc        @ 5120   : W_fc fully converted      (256 P0 arrivals)
//   qdone[64]  @ 8192   : QKV 128-row panel ready   (12 P1 arrivals each)
//   adone[64]  @ 12288  : AO 128-row panel ready    (16 P2 arrivals each)
// ---------------------------------------------------------------------------

// ---------------------------------------------------------------------------
// P0 unit: X transpose-convert (unit b of 1024) + weight convert chunk b.
// ---------------------------------------------------------------------------
__device__ __forceinline__ void prep_unit(char* sm, int b,
    const float* __restrict__ input, unsigned short* __restrict__ Xh,
    const float* __restrict__ W_in, unsigned short* __restrict__ Winh,
    const float* __restrict__ W_fc, unsigned short* __restrict__ Wfch)
{
    const int t = threadIdx.x;
    float (*ts)[65] = (float(*)[65])sm;
    const int n  = b >> 8, rm = b & 255;
    const int i0 = (rm & 31) * 64, c0 = (rm >> 5) * 64;
    const int tx = t & 63, ty = t >> 6;
    #pragma unroll
    for (int s = 0; s < 16; ++s) {
        const int c = s * 4 + ty;
        ts[c][tx] = input[((size_t)(n * C_IN + c0 + c)) * W_SEQ + i0 + tx];
    }
    __syncthreads();
    const int c8 = t & 7, il = t >> 3;
    #pragma unroll
    for (int s = 0; s < 2; ++s) {
        const int i = il + 32 * s;
        u16x8 hv;
        #pragma unroll
        for (int e = 0; e < 8; ++e) hv[e] = f2bf(ts[c8 * 8 + e][i]);
        *(u16x8*)(&Xh[((size_t)(n * W_SEQ + i0 + i)) * C_IN + c0 + c8 * 8]) = hv;
    }
    const int idx = b * 256 + t;               // [0, 262144) == N1_4 + N2_4
    if (idx < N1_4) {
        const float4 v = ((const float4*)W_in)[idx];
        ushort4 hh; hh.x = f2bf(v.x); hh.y = f2bf(v.y); hh.z = f2bf(v.z); hh.w = f2bf(v.w);
        ((ushort4*)Winh)[idx] = hh;
    } else {
        const int j = idx - N1_4;
        const float4 v = ((const float4*)W_fc)[j];
        ushort4 hh; hh.x = f2bf(v.x); hh.y = f2bf(v.y); hh.z = f2bf(v.z); hh.w = f2bf(v.w);
        ((ushort4*)Wfch)[j] = hh;
    }
}

// ---------------------------------------------------------------------------
// GEMM body: C = A * B^T (+bias), K = 512, 128x128 tile, 32 KB LDS arena.
// Epilogue: ni-innermost so each 64B C line is completed by consecutive
// stores (write-combining friendly; tests the write-amp hypothesis).
// EPI 0: bf16 store C[row*ldc+col] = acc + bias[col]
// EPI 1: f32 store out[((col>>11)*512+row)*2048 + (col&2047)] = acc + bias[row]
// ---------------------------------------------------------------------------
template<int EPI>
__device__ __forceinline__ void gemm_body(char* sm, int bx, int by,
    const unsigned short* __restrict__ A, const unsigned short* __restrict__ B,
    const float* __restrict__ bias, void* __restrict__ Cv, const int ldc)
{
    const int t = threadIdx.x;
    const int l = t & 63, w = t >> 6;
    const int m0 = by * 128, n0 = bx * 128;
    const int wm = w >> 1, wn = w & 1;

    const int subrow = l >> 3;
    const int swz    = ((l & 7) ^ subrow) << 4;
    const char* pA = (const char*)A + (size_t)m0 * 1024 + swz;
    const char* pB = (const char*)B + (size_t)n0 * 1024 + swz;

    const int frow = l & 15;
    f32x4 acc[4][4] = {};

    for (int k0 = 0; k0 < 512; k0 += 64) {
        const int kb = k0 * 2;
        #pragma unroll
        for (int c = 0; c < 4; ++c) {
            const int q = 4 * w + c;
            const size_t roff = (size_t)(q * 8 + subrow) * 1024 + kb;
            gld16(pA + roff, sm +         q * 1024);
            gld16(pB + roff, sm + 16384 + q * 1024);
        }
        __syncthreads();
        #pragma unroll
        for (int kk = 0; kk < 2; ++kk) {
            const int cswz = (kk * 64 + ((l >> 4) << 4)) ^ ((l & 7) << 4);
            bf16x8 a[4], b[4];
            #pragma unroll
            for (int mi = 0; mi < 4; ++mi)
                a[mi] = *(const bf16x8*)(sm + (wm * 64 + mi * 16 + frow) * 128 + cswz);
            #pragma unroll
            for (int ni = 0; ni < 4; ++ni)
                b[ni] = *(const bf16x8*)(sm + 16384 + (wn * 64 + ni * 16 + frow) * 128 + cswz);
            #pragma unroll
            for (int mi = 0; mi < 4; ++mi)
                #pragma unroll
                for (int ni = 0; ni < 4; ++ni)
                    acc[mi][ni] = __builtin_amdgcn_mfma_f32_16x16x32_bf16(a[mi], b[ni], acc[mi][ni], 0, 0, 0);
        }
        __syncthreads();
    }

    const int g = l >> 4;
    int cols[4]; float bcol[4];
    #pragma unroll
    for (int ni = 0; ni < 4; ++ni) {
        cols[ni] = n0 + wn * 64 + ni * 16 + frow;
        bcol[ni] = (EPI == 0) ? bias[cols[ni]] : 0.f;
    }
    #pragma unroll
    for (int mi = 0; mi < 4; ++mi) {
        #pragma unroll
        for (int r = 0; r < 4; ++r) {
            const int rowg = m0 + wm * 64 + mi * 16 + g * 4 + r;
            float brow = 0.f;
            if (EPI == 1) brow = bias[rowg];
            #pragma unroll
            for (int ni = 0; ni < 4; ++ni) {
                const float v = acc[mi][ni][r];
                if (EPI == 0) {
                    ((unsigned short*)Cv)[(size_t)rowg * ldc + cols[ni]] = f2bf(v + bcol[ni]);
                } else {
                    const int nb = cols[ni] >> 11, ii = cols[ni] & (W_SEQ - 1);
                    ((float*)Cv)[((size_t)(nb * OUT_CH + rowg)) * W_SEQ + ii] = v + brow;
                }
            }
        }
    }
}

// ---------------------------------------------------------------------------
// Banded MFMA attention body (proven attn4 math). LDS: K[96][144B] @0
// (P[64][208B] overlays), VT[64][256B] @13824 (chunk-XOR swizzle),
// mask f32[96] @30208. 30592 B within the 32 KB arena.
// ---------------------------------------------------------------------------
#define VT_OFF  13824
#define MSK_OFF 30208

__device__ __forceinline__ void attn_body(char* sm, int blk,
    const unsigned short* __restrict__ qkv, const float* __restrict__ mask,
    unsigned short* __restrict__ aoh)
{
    const int t = threadIdx.x, l = t & 63, w = t >> 6;
    const int i0 = (blk & 31) * 64, h = (blk >> 5) & 7, n = blk >> 8;
    const int lr = l & 15, lg = l >> 4;

    const char* tb = (const char*)qkv + ((size_t)n * W_SEQ * QKV_CH + h * 192) * 2;

    const int r8 = l >> 3, c8 = l & 7;
    #pragma unroll
    for (int it = 0; it < 3; ++it) {
        const int jl = w * 24 + it * 8 + r8;
        const int jg = i0 - 16 + jl;
        bf16x8 kv = {}, vv = {};
        if (jg >= 0 && jg < W_SEQ) {
            const char* rp = tb + (size_t)jg * 3072;
            kv = *(const bf16x8*)(rp + 128 + c8 * 16);
            vv = *(const bf16x8*)(rp + 256 + c8 * 16);
        }
        *(bf16x8*)(sm + jl * 144 + c8 * 16) = kv;
        const int J0 = jl >> 3;
        #pragma unroll
        for (int e = 0; e < 8; ++e) {
            const int d = c8 * 8 + e;
            const int fold = ((d >> 3) ^ d) & 7;
            *(unsigned short*)(sm + VT_OFF + d * 256 + (((J0 ^ fold) << 4) | ((jl & 7) * 2)))
                = (unsigned short)vv[e];
        }
    }
    bf16x8 qh[2];
    {
        const char* qrow = tb + (size_t)(i0 + w * 16 + lr) * 3072 + lg * 16;
        qh[0] = *(const bf16x8*)(qrow);
        qh[1] = *(const bf16x8*)(qrow + 64);
    }
    if (t < 96) {
        const int jg = i0 - 16 + t;
        *(float*)(sm + MSK_OFF + t * 4) = (jg >= 0 && jg < W_SEQ) ? mask[n * W_SEQ + jg] : 0.f;
    }
    __syncthreads();

    f32x4 sacc[6] = {};
    #pragma unroll
    for (int nf = 0; nf < 6; ++nf) {
        #pragma unroll
        for (int kk = 0; kk < 2; ++kk) {
            const bf16x8 kh = *(const bf16x8*)(sm + (nf * 16 + lr) * 144 + kk * 64 + lg * 16);
            sacc[nf] = __builtin_amdgcn_mfma_f32_16x16x32_bf16(qh[kk], kh, sacc[nf], 0, 0, 0);
        }
    }
    __syncthreads();

    float mv[6];
    #pragma unroll
    for (int nf = 0; nf < 6; ++nf)
        mv[nf] = *(const float*)(sm + MSK_OFF + (nf * 16 + lr) * 4);

    #pragma unroll
    for (int r = 0; r < 4; ++r) {
        const int ri = w * 16 + lg * 4 + r;
        float sv[6], mrow = -1.0e30f;
        #pragma unroll
        for (int nf = 0; nf < 6; ++nf) {
            const int jcol = nf * 16 + lr;
            const bool valid = (jcol > ri) && (jcol <= ri + 31) && (mv[nf] > 0.5f);
            const float s = valid ? sacc[nf][r] * 0.015625f : -1.0e30f;
            sv[nf] = s;
            mrow = fmaxf(mrow, s);
        }
        #pragma unroll
        for (int off = 1; off <= 8; off <<= 1) mrow = fmaxf(mrow, __shfl_xor(mrow, off));
        float ls = 0.f;
        #pragma unroll
        for (int nf = 0; nf < 6; ++nf) {
            float pp = __expf(sv[nf] - mrow);
            pp = (sv[nf] > -1.0e29f) ? pp : 0.f;
            sv[nf] = pp;
            ls += pp;
        }
        #pragma unroll
        for (int off = 1; off <= 8; off <<= 1) ls += __shfl_xor(ls, off);
        const float rinv = (ls > 0.f) ? 1.f / ls : 0.f;
        #pragma unroll
        for (int nf = 0; nf < 6; ++nf)
            *(unsigned short*)(sm + ri * 208 + (nf * 16 + lr) * 2) = f2bf(sv[nf] * rinv);
    }

    f32x4 oacc[4] = {};
    #pragma unroll
    for (int ks = 0; ks < 3; ++ks) {
        const bf16x8 pah = *(const bf16x8*)(sm + (w * 16 + lr) * 208 + ks * 64 + lg * 16);
        #pragma unroll
        for (int nf2 = 0; nf2 < 4; ++nf2) {
            const int dd = nf2 * 16 + lr;
            const int fold = ((dd >> 3) ^ dd) & 7;
            const bf16x8 vb = *(const bf16x8*)(sm + VT_OFF + dd * 256 + (((4 * ks + lg) ^ fold) << 4));
            oacc[nf2] = __builtin_amdgcn_mfma_f32_16x16x32_bf16(pah, vb, oacc[nf2], 0, 0, 0);
        }
    }

    #pragma unroll
    for (int nf2 = 0; nf2 < 4; ++nf2) {
        #pragma unroll
        for (int r = 0; r < 4; ++r) {
            const int ri = w * 16 + lg * 4 + r;
            aoh[((size_t)(n * W_SEQ + i0 + ri)) * ATTND + h * 64 + nf2 * 16 + lr] = f2bf(oacc[nf2][r]);
        }
    }
}

// ---------------------------------------------------------------------------
// Fused persistent kernel: fully flag-driven (no full-grid barrier).
// DAG: P0 (no waits) -> xdone/wpanel/wfc -> P1 -> qdone -> P2 -> adone -> P3.
// REQUIRES gridDim.x == 1024 fully co-resident (host-verified occ >= 4).
// ---------------------------------------------------------------------------
__global__ __launch_bounds__(256, 4) void fused_all_k(
    const float* __restrict__ input, const float* __restrict__ mask,
    const float* __restrict__ W_in,  const float* __restrict__ b_in,
    const float* __restrict__ W_fc,  const float* __restrict__ b_fc,
    float* __restrict__ out,
    unsigned short* __restrict__ QKVh, unsigned short* __restrict__ AOh,
    unsigned short* __restrict__ Winh, unsigned short* __restrict__ Wfch,
    unsigned short* __restrict__ Xh, unsigned* __restrict__ flg)
{
    __shared__ __align__(16) char sm[32768];
    const int b = blockIdx.x;
    unsigned* xdone  = flg;            // byte 0
    unsigned* wpanel = flg + 1024;     // byte 4096
    unsigned* wfc    = flg + 1280;     // byte 5120
    unsigned* qdone  = flg + 2048;     // byte 8192
    unsigned* adone  = flg + 3072;     // byte 12288

    // ---- P0: prep (all 1024 blocks, one unit each) ----
    prep_unit(sm, b, input, Xh, W_in, Winh, W_fc, Wfch);
    __syncthreads();
    if (threadIdx.x == 0) {
        __threadfence();
        atomicAdd(xdone + ((b >> 8) * 16 + ((b & 31) >> 1)) * 16, 1u);
        if (b < 768) atomicAdd(wpanel + (b >> 6) * 16, 1u);
        else         atomicAdd(wfc, 1u);
    }

    // ---- P1: GEMM1 (768 tiles, XCD-grouped; n=3 panels produced first) ----
    if (b < 768) {
        const int y8 = b & 7, r = b >> 3;
        const int bx = r % 12;
        const int by = (((r / 12) + 6) & 7) * 8 + y8;
        if (threadIdx.x == 0) {
            while (ld_flag(wpanel + bx * 16) < 64u) __builtin_amdgcn_s_sleep(2);
            while (ld_flag(xdone  + by * 16) < 16u) __builtin_amdgcn_s_sleep(2);
            __threadfence();
        }
        __syncthreads();
        gemm_body<0>(sm, bx, by, Xh, Winh, b_in, QKVh, QKV_CH);
        __syncthreads();
        if (threadIdx.x == 0) {
            __threadfence();
            atomicAdd(qdone + by * 16, 1u);
        }
    }

    // ---- P2: attention (all 1024 blocks, one tile each) ----
    {
        const int n = b >> 8, i0 = (b & 31) * 64;
        const int row1 = n * W_SEQ + ((i0 >= 16) ? i0 - 16 : 0);
        const int row2 = n * W_SEQ + ((i0 + 79 <= W_SEQ - 1) ? i0 + 79 : W_SEQ - 1);
        const int t1 = row1 >> 7, t2 = row2 >> 7;
        if (threadIdx.x == 0) {
            while (ld_flag(qdone + t1 * 16) < 12u) __builtin_amdgcn_s_sleep(2);
            while (ld_flag(qdone + t2 * 16) < 12u) __builtin_amdgcn_s_sleep(2);
            __threadfence();
        }
        __syncthreads();
        attn_body(sm, b, QKVh, mask, AOh);
        __syncthreads();
        if (threadIdx.x == 0) {
            __threadfence();
            const int panel = n * 16 + (i0 >> 7);
            atomicAdd(adone + panel * 16, 1u);
        }
    }

    // ---- P3: GEMM2 (256 tiles) ----
    if (b < 256) {
        const int bx = b >> 2, by = b & 3;
        if (threadIdx.x == 0) {
            while (ld_flag(wfc) < 256u) __builtin_amdgcn_s_sleep(2);
            while (ld_flag(adone + bx * 16) < 16u) __builtin_amdgcn_s_sleep(2);
            __threadfence();
        }
        __syncthreads();
        gemm_body<1>(sm, bx, by, Wfch, AOh, b_fc, out, 0);
    }
}

// ---------------------------------------------------------------------------
// Fallback separate kernels (proven path) over the same bodies.
// ---------------------------------------------------------------------------
__global__ __launch_bounds__(256, 4) void prep_sep_k(
    const float* __restrict__ input, unsigned short* __restrict__ Xh,
    const float* __restrict__ W_in, unsigned short* __restrict__ Winh,
    const float* __restrict__ W_fc, unsigned short* __restrict__ Wfch)
{
    __shared__ __align__(16) char sm[32768];
    prep_unit(sm, blockIdx.x, input, Xh, W_in, Winh, W_fc, Wfch);
}
__global__ __launch_bounds__(256, 4) void gemm1_sep_k(
    const unsigned short* __restrict__ A, const unsigned short* __restrict__ B,
    const float* __restrict__ bias, unsigned short* __restrict__ C)
{
    __shared__ __align__(16) char sm[32768];
    const int d = blockIdx.x, y8 = d & 7, r = d >> 3;
    gemm_body<0>(sm, r % 12, (((r / 12) + 6) & 7) * 8 + y8, A, B, bias, C, QKV_CH);
}
__global__ __launch_bounds__(256, 4) void attn_sep_k(
    const unsigned short* __restrict__ qkv, const float* __restrict__ mask,
    unsigned short* __restrict__ aoh)
{
    __shared__ __align__(16) char sm[32768];
    attn_body(sm, blockIdx.x, qkv, mask, aoh);
}
__global__ __launch_bounds__(256, 4) void gemm2_sep_k(
    const unsigned short* __restrict__ A, const unsigned short* __restrict__ B,
    const float* __restrict__ bias, float* __restrict__ out)
{
    __shared__ __align__(16) char sm[32768];
    gemm_body<1>(sm, blockIdx.x >> 2, blockIdx.x & 3, A, B, bias, out, 0);
}

extern "C" void kernel_launch(void* const* d_in, const int* in_sizes, int n_in,
                              void* d_out, int out_size, void* d_ws, size_t ws_size,
                              hipStream_t stream)
{
    const float* input = (const float*)d_in[0];
    const float* mask  = (const float*)d_in[1];
    const float* W_in  = (const float*)d_in[2];
    const float* b_in  = (const float*)d_in[3];
    const float* W_fc  = (const float*)d_in[4];
    const float* b_fc  = (const float*)d_in[5];
    float* out = (float*)d_out;
    char* ws = (char*)d_ws;

    // Workspace layout:
    //   QKVh [0,        25165824)  bf16[8192][1536]
    //   AOh  [25165824, 33554432)  bf16[8192][512]
    //   Winh [33554432, 35127296)  bf16[1536][512]
    //   Wfch [35127296, 35651584)  bf16[512][512]
    //   Xh   [35651584, 44040192)  bf16[8192][512]
    //   flg  [46137344, 46153728)  16 KB flag region
    unsigned short* QKVh = (unsigned short*)ws;
    unsigned short* AOh  = (unsigned short*)(ws + 25165824);
    unsigned short* Winh = (unsigned short*)(ws + 33554432);
    unsigned short* Wfch = (unsigned short*)(ws + 35127296);
    unsigned short* Xh   = (unsigned short*)(ws + 35651584);
    unsigned*       flg  = (unsigned*)(ws + 46137344);

    // Host-side occupancy check (pure query, deterministic, capture-safe).
    int occ = 0;
    hipOccupancyMaxActiveBlocksPerMultiprocessor(&occ, fused_all_k, 256, 0);

    if (occ >= 4) {
        hipMemsetAsync(flg, 0, 16384, stream);
        fused_all_k<<<dim3(1024), 256, 0, stream>>>(
            input, mask, W_in, b_in, W_fc, b_fc, out,
            QKVh, AOh, Winh, Wfch, Xh, flg);
    } else {
        prep_sep_k <<<dim3(1024), 256, 0, stream>>>(input, Xh, W_in, Winh, W_fc, Wfch);
        gemm1_sep_k<<<dim3(768),  256, 0, stream>>>(Xh, Winh, b_in, QKVh);
        attn_sep_k <<<dim3(1024), 256, 0, stream>>>(QKVh, mask, AOh);
        gemm2_sep_k<<<dim3(256),  256, 0, stream>>>(Wfch, AOh, b_fc, out);
    }
}